// Round 8
// baseline (7827.010 us; speedup 1.0000x reference)
//
#include <hip/hip_runtime.h>
#include <hip/hip_bf16.h>

typedef short bf16x8 __attribute__((ext_vector_type(8)));
typedef float fx4 __attribute__((ext_vector_type(4)));
typedef unsigned short u16;
typedef u16 u16x4 __attribute__((ext_vector_type(4)));
typedef unsigned u32;

#define TT 512
#define BB 64
#define II 256
#define HH 512
#define OO 256
#define GRID_WG 128

__device__ __forceinline__ u16 f2bf(float f) {
    union { float f; unsigned u; } v; v.f = f;
    unsigned r = v.u + 0x7fffu + ((v.u >> 16) & 1u);
    return (u16)(r >> 16);
}

__device__ __forceinline__ float fsig(float x) {
    return 1.0f / (1.0f + exp2f(x * -1.4426950408889634f));
}
__device__ __forceinline__ float ftanh(float x) {
    return 2.0f * fsig(2.0f * x) - 1.0f;
}

// ---------------- prep: bf16 conversions + zero init ----------------
__global__ void prep_kernel(const float* __restrict__ X, const float* __restrict__ Whq,
                            u16* __restrict__ Xb, u16* __restrict__ WqT,
                            u16* __restrict__ Hb, int* __restrict__ flags) {
    long gid = (long)blockIdx.x * blockDim.x + threadIdx.x;
    long stride = (long)gridDim.x * blockDim.x;
    const float4* X4 = (const float4*)X;
    for (long i = gid; i < 2097152; i += stride) {
        float4 v = X4[i];
        u16x4 o;
        o.x = f2bf(v.x); o.y = f2bf(v.y); o.z = f2bf(v.z); o.w = f2bf(v.w);
        ((u16x4*)Xb)[i] = o;
    }
    for (long i = gid; i < 131072; i += stride) {
        int o = (int)(i >> 9), k = (int)(i & 511);
        WqT[i] = f2bf(Whq[(long)k * 256 + o]);
    }
    // zero both parities of Hbuf: 2*64*512 u16 = 32768 ints
    for (long i = gid; i < 32768; i += stride) ((int*)Hb)[i] = 0;
    if (gid < 256) flags[gid] = 0;
}

// ---------------- recurrence: cooperative, 128 WGs x 256 thr ----------------
// r5-proven skeleton, consumer-side change ONLY:
//   producer (UNCHANGED from r5-pass): plain H stores -> __syncthreads ->
//     tid0 RELEASE-store flag (compiler emits buffer_wbl2 + waitcnt: H is
//     at the LLC before the flag is visible).
//   consumer (CHANGED): H read via RELAXED agent-scope atomic u32 loads —
//     the exact primitive the r3/r5 flag-polls prove bypasses stale L1/L2
//     and reads the coherence point. NO acquire fence -> no per-step
//     buffer_inv L2 walk, X/weights stay cache-warm all 512 steps.
__global__ __launch_bounds__(256, 1)
void lstm_rec(const u16* __restrict__ Xb, u16* __restrict__ Hb, int* __restrict__ flags,
              const float* __restrict__ Wxi, const float* __restrict__ Wxf,
              const float* __restrict__ Wxo, const float* __restrict__ Wxg,
              const float* __restrict__ Whi, const float* __restrict__ Whf,
              const float* __restrict__ Who, const float* __restrict__ Whg,
              const float* __restrict__ bi, const float* __restrict__ bf_,
              const float* __restrict__ bo, const float* __restrict__ bg,
              float* __restrict__ Hs, float* __restrict__ Cs) {
    const int wg   = blockIdx.x;          // 0..127, owns h in [wg*4, wg*4+4)
    const int tid  = threadIdx.x;
    const int lane = tid & 63;
    const int wave = tid >> 6;            // 4 waves, 16 batch rows each
    const int c    = lane & 15;           // MFMA col / A-row-within-tile index
    const int hi4  = lane >> 4;           // 0..3
    const int gate = c >> 2;              // 0=i 1=f 2=o 3=g
    const int hloc = c & 3;
    const int h    = wg * 4 + hloc;       // global hidden column

    const float* Wx = (gate == 0) ? Wxi : (gate == 1) ? Wxf : (gate == 2) ? Wxo : Wxg;
    const float* Wh = (gate == 0) ? Whi : (gate == 1) ? Whf : (gate == 2) ? Who : Whg;
    const float* bp = (gate == 0) ? bi  : (gate == 1) ? bf_ : (gate == 2) ? bo  : bg;
    const float biasv = bp[h];

    // ---- preload this lane's B fragments (whole K=768) into registers ----
    bf16x8 Bf[24];
#pragma unroll
    for (int kt = 0; kt < 24; ++kt) {
        bf16x8 tmp;
#pragma unroll
        for (int j = 0; j < 8; ++j) {
            int k = kt * 32 + hi4 * 8 + j;
            float w = (k < II) ? Wx[(long)k * HH + h] : Wh[(long)(k - II) * HH + h];
            tmp[j] = (short)f2bf(w);
        }
        Bf[kt] = tmp;
    }

    const int arow = wave * 16 + c;                 // batch row this lane loads for A
    const int browbase = wave * 16 + hi4 * 4;       // D-rows base for this lane
    const int srcbase = (lane & 48) | hloc;         // shfl source base

    // ---- preload X fragments for t=0 (plain cached loads) ----
    bf16x8 xf[8];
    {
        const u16* xp = Xb + (long)arow * II + hi4 * 8;
#pragma unroll
        for (int kt = 0; kt < 8; ++kt) xf[kt] = *(const bf16x8*)(xp + kt * 32);
    }

    float cst[4] = {0.f, 0.f, 0.f, 0.f};

    for (int t = 0; t < TT; ++t) {
        // 1. issue ALL H loads first, as relaxed agent atomic u32 loads
        //    (bypass L1/L2; read the LLC, fresh by flag release-ordering).
        bf16x8 hf[16];
        const u32* hp32 = (const u32*)(Hb + ((t & 1) ? (long)BB * HH : 0)
                                          + (long)arow * HH + hi4 * 8);
#pragma unroll
        for (int kt = 0; kt < 16; ++kt) {
            union { u32 d[4]; bf16x8 v; } uu;
            uu.d[0] = __hip_atomic_load(hp32 + kt * 16 + 0, __ATOMIC_RELAXED, __HIP_MEMORY_SCOPE_AGENT);
            uu.d[1] = __hip_atomic_load(hp32 + kt * 16 + 1, __ATOMIC_RELAXED, __HIP_MEMORY_SCOPE_AGENT);
            uu.d[2] = __hip_atomic_load(hp32 + kt * 16 + 2, __ATOMIC_RELAXED, __HIP_MEMORY_SCOPE_AGENT);
            uu.d[3] = __hip_atomic_load(hp32 + kt * 16 + 3, __ATOMIC_RELAXED, __HIP_MEMORY_SCOPE_AGENT);
            hf[kt] = uu.v;
        }

        // 2. X-part MFMAs (registers only — overlap H-load LLC latency)
        fx4 acc0 = {biasv, biasv, biasv, biasv};
        fx4 acc1 = {0.f, 0.f, 0.f, 0.f};
#pragma unroll
        for (int kt = 0; kt < 8; ++kt) {
            if (kt & 1) acc1 = __builtin_amdgcn_mfma_f32_16x16x32_bf16(xf[kt], Bf[kt], acc1, 0, 0, 0);
            else        acc0 = __builtin_amdgcn_mfma_f32_16x16x32_bf16(xf[kt], Bf[kt], acc0, 0, 0, 0);
        }

        // 3. prefetch next step's X tile (plain cached loads — L2 stays warm,
        //    no invalidation ever happens now)
        bf16x8 xf2[8];
        if (t < TT - 1) {
            const u16* xp = Xb + ((long)((t + 1) * BB + arow)) * II + hi4 * 8;
#pragma unroll
            for (int kt = 0; kt < 8; ++kt) xf2[kt] = *(const bf16x8*)(xp + kt * 32);
        }

        // 4. H-part MFMAs
#pragma unroll
        for (int kt = 0; kt < 16; ++kt) {
            if (kt & 1) acc1 = __builtin_amdgcn_mfma_f32_16x16x32_bf16(hf[kt], Bf[8 + kt], acc1, 0, 0, 0);
            else        acc0 = __builtin_amdgcn_mfma_f32_16x16x32_bf16(hf[kt], Bf[8 + kt], acc0, 0, 0, 0);
        }
        fx4 acc = acc0 + acc1;

        // 5. gather gate preacts + elementwise gate math
        float cn[4], hn[4];
#pragma unroll
        for (int r = 0; r < 4; ++r) {
            float pi = __shfl(acc[r], srcbase + 0);
            float pf = __shfl(acc[r], srcbase + 4);
            float po = __shfl(acc[r], srcbase + 8);
            float pg = __shfl(acc[r], srcbase + 12);
            float ig = fsig(pi);
            float fg = fsig(pf);
            float og = fsig(po);
            float gg = ftanh(pg);
            float cv = fg * cst[r] + ig * gg;
            cst[r] = cv;
            cn[r] = cv;
            hn[r] = og * ftanh(cv);
        }

        // 6. H stores for next step (plain stores; published by the release)
        if (c >= 4 && c < 8) {
            u16* HbW = Hb + (long)(((t + 1) & 1)) * BB * HH;
#pragma unroll
            for (int r = 0; r < 4; ++r)
                HbW[(long)(browbase + r) * HH + h] = f2bf(hn[r]);
        }

        // 7. join WG (drains each wave's stores to L2), then publish:
        //    RELEASE store emits buffer_wbl2 + waitcnt before the flag, so
        //    flag-visible-at-LLC implies H-visible-at-LLC.  [proven r3/r5]
        __syncthreads();
        if (tid == 0)
            __hip_atomic_store(&flags[wg], t + 1, __ATOMIC_RELEASE, __HIP_MEMORY_SCOPE_AGENT);

        // 8. Hs/Cs fp32 stores — off the critical path, nontemporal
        if (c < 4) {
            float* HsT = Hs + (long)t * BB * HH;
            float* CsT = Cs + (long)t * BB * HH;
#pragma unroll
            for (int r = 0; r < 4; ++r) {
                __builtin_nontemporal_store(hn[r], &HsT[(long)(browbase + r) * HH + h]);
                __builtin_nontemporal_store(cn[r], &CsT[(long)(browbase + r) * HH + h]);
            }
        }

        // 9. wait for all WGs (relaxed poll — proven to observe remote flags)
        if (tid < GRID_WG) {
            while (__hip_atomic_load(&flags[tid], __ATOMIC_RELAXED, __HIP_MEMORY_SCOPE_AGENT) < t + 1)
                __builtin_amdgcn_s_sleep(1);
        }
        __syncthreads();
        // pin: nothing (esp. next step's atomic H loads) moves above here
        __builtin_amdgcn_sched_barrier(0);

        // rotate X prefetch
        if (t < TT - 1) {
#pragma unroll
            for (int kt = 0; kt < 8; ++kt) xf[kt] = xf2[kt];
        }
    }
}

// ---------------- output GEMM: out = Hs @ WqT^T + bq ----------------
__global__ __launch_bounds__(256) void outgemm(const float* __restrict__ Hs,
                                               const u16* __restrict__ WqT,
                                               const float* __restrict__ bq,
                                               float* __restrict__ outp) {
    const int lane = threadIdx.x & 63, wave = threadIdx.x >> 6;
    const int cl = lane & 15, hi4 = lane >> 4;
    const int rowbase = blockIdx.x * 64 + wave * 16;
    const int colbase = blockIdx.y * 64;

    const float* Ap = Hs + (long)(rowbase + cl) * HH + hi4 * 8;
    fx4 acc[4];
#pragma unroll
    for (int n = 0; n < 4; ++n) acc[n] = (fx4){0.f, 0.f, 0.f, 0.f};

#pragma unroll
    for (int kt = 0; kt < 16; ++kt) {
        const float4* a4 = (const float4*)(Ap + kt * 32);
        float4 a0 = a4[0], a1 = a4[1];
        bf16x8 af;
        af[0] = (short)f2bf(a0.x); af[1] = (short)f2bf(a0.y);
        af[2] = (short)f2bf(a0.z); af[3] = (short)f2bf(a0.w);
        af[4] = (short)f2bf(a1.x); af[5] = (short)f2bf(a1.y);
        af[6] = (short)f2bf(a1.z); af[7] = (short)f2bf(a1.w);
#pragma unroll
        for (int n = 0; n < 4; ++n) {
            bf16x8 bfg = *(const bf16x8*)(WqT + (long)(colbase + n * 16 + cl) * HH + kt * 32 + hi4 * 8);
            acc[n] = __builtin_amdgcn_mfma_f32_16x16x32_bf16(af, bfg, acc[n], 0, 0, 0);
        }
    }
#pragma unroll
    for (int n = 0; n < 4; ++n) {
        int col = colbase + n * 16 + cl;
        float bv = bq[col];
#pragma unroll
        for (int r = 0; r < 4; ++r) {
            int row = rowbase + hi4 * 4 + r;
            outp[(long)row * OO + col] = acc[n][r] + bv;
        }
    }
}

extern "C" void kernel_launch(void* const* d_in, const int* in_sizes, int n_in,
                              void* d_out, int out_size, void* d_ws, size_t ws_size,
                              hipStream_t stream) {
    const float* X   = (const float*)d_in[0];
    const float* Wxi = (const float*)d_in[1];
    const float* Wxf = (const float*)d_in[2];
    const float* Wxo = (const float*)d_in[3];
    const float* Wxg = (const float*)d_in[4];
    const float* Whi = (const float*)d_in[5];
    const float* Whf = (const float*)d_in[6];
    const float* Who = (const float*)d_in[7];
    const float* Whg = (const float*)d_in[8];
    const float* bi  = (const float*)d_in[9];
    const float* bf_ = (const float*)d_in[10];
    const float* bo  = (const float*)d_in[11];
    const float* bg  = (const float*)d_in[12];
    const float* Whq = (const float*)d_in[13];
    const float* bq  = (const float*)d_in[14];

    float* outp = (float*)d_out;
    float* Hs = outp + (size_t)TT * BB * OO;          // 8388608
    float* Cs = Hs   + (size_t)TT * BB * HH;          // +16777216

    u16* Xb  = (u16*)d_ws;                            // 8388608 u16
    u16* WqT = Xb + (size_t)TT * BB * II;             // 131072 u16
    u16* Hb  = WqT + (size_t)OO * HH;                 // 65536 u16 (2 parities)
    int* flags = (int*)(Hb + (size_t)2 * BB * HH);    // 256 ints

    prep_kernel<<<2048, 256, 0, stream>>>(X, Whq, Xb, WqT, Hb, flags);

    void* args[17] = {
        (void*)&Xb, (void*)&Hb, (void*)&flags,
        (void*)&Wxi, (void*)&Wxf, (void*)&Wxo, (void*)&Wxg,
        (void*)&Whi, (void*)&Whf, (void*)&Who, (void*)&Whg,
        (void*)&bi, (void*)&bf_, (void*)&bo, (void*)&bg,
        (void*)&Hs, (void*)&Cs
    };
    hipError_t ce = hipLaunchCooperativeKernel((void*)lstm_rec, dim3(GRID_WG), dim3(256), args, 0, stream);
    if (ce != hipSuccess) {
        // Fallback: plain launch. 128 WGs of 256 thr / 0 LDS on 256 CUs are
        // trivially co-resident (>=1 block/CU capacity), so the in-kernel
        // flag barrier is deadlock-free. Same work either way.
        lstm_rec<<<dim3(GRID_WG), dim3(256), 0, stream>>>(
            Xb, Hb, flags, Wxi, Wxf, Wxo, Wxg, Whi, Whf, Who, Whg,
            bi, bf_, bo, bg, Hs, Cs);
    }

    outgemm<<<dim3(512, 4), 256, 0, stream>>>(Hs, WqT, bq, outp);
}

// Round 9
// 6032.073 us; speedup vs baseline: 1.2976x; 1.2976x over previous
//
#include <hip/hip_runtime.h>
#include <hip/hip_bf16.h>

typedef short bf16x8 __attribute__((ext_vector_type(8)));
typedef float fx4 __attribute__((ext_vector_type(4)));
typedef unsigned short u16;
typedef u16 u16x4 __attribute__((ext_vector_type(4)));
typedef unsigned u32;

#define TT 512
#define BB 64
#define II 256
#define HH 512
#define OO 256
#define NSTREAM 4        // independent batch-row groups of 16
#define WGS_PER_STREAM 16
#define GRID_WG (NSTREAM * WGS_PER_STREAM)   // 64

__device__ __forceinline__ u16 f2bf(float f) {
    union { float f; unsigned u; } v; v.f = f;
    unsigned r = v.u + 0x7fffu + ((v.u >> 16) & 1u);
    return (u16)(r >> 16);
}

__device__ __forceinline__ float fsig(float x) {
    return 1.0f / (1.0f + exp2f(x * -1.4426950408889634f));
}
__device__ __forceinline__ float ftanh(float x) {
    return 2.0f * fsig(2.0f * x) - 1.0f;
}

// ---------------- prep: bf16 conversions + zero init ----------------
// Adds WcatT [2048][768]: column-major-by-gate-tile concatenated weights.
// Column j: tile t=j>>4, c=j&15, gate=c>>2, h=t*4+(c&3).  Row k<256 -> Wx,
// else Wh.  B-fragment for MFMA col c of tile t is then 8 consecutive bf16.
__global__ void prep_kernel(const float* __restrict__ X, const float* __restrict__ Whq,
                            const float* __restrict__ Wxi, const float* __restrict__ Wxf,
                            const float* __restrict__ Wxo, const float* __restrict__ Wxg,
                            const float* __restrict__ Whi, const float* __restrict__ Whf,
                            const float* __restrict__ Who, const float* __restrict__ Whg,
                            u16* __restrict__ Xb, u16* __restrict__ WqT,
                            u16* __restrict__ Wcat, u16* __restrict__ Hb,
                            int* __restrict__ flags) {
    long gid = (long)blockIdx.x * blockDim.x + threadIdx.x;
    long stride = (long)gridDim.x * blockDim.x;
    const float4* X4 = (const float4*)X;
    for (long i = gid; i < 2097152; i += stride) {
        float4 v = X4[i];
        u16x4 o;
        o.x = f2bf(v.x); o.y = f2bf(v.y); o.z = f2bf(v.z); o.w = f2bf(v.w);
        ((u16x4*)Xb)[i] = o;
    }
    for (long i = gid; i < 131072; i += stride) {
        int o = (int)(i >> 9), k = (int)(i & 511);
        WqT[i] = f2bf(Whq[(long)k * 256 + o]);
    }
    // WcatT: 2048 * 768 = 1572864 elems
    for (long i = gid; i < 1572864; i += stride) {
        int j = (int)(i / 768), k = (int)(i - (long)j * 768);
        int cc = j & 15, tg = j >> 4;
        int gate = cc >> 2;
        int h = tg * 4 + (cc & 3);
        const float* W;
        if (k < II) W = (gate == 0) ? Wxi : (gate == 1) ? Wxf : (gate == 2) ? Wxo : Wxg;
        else        W = (gate == 0) ? Whi : (gate == 1) ? Whf : (gate == 2) ? Who : Whg;
        int kk = (k < II) ? k : k - II;
        Wcat[i] = f2bf(W[(long)kk * HH + h]);
    }
    // zero H exchange buffers: 2 parities x 4 streams x 16 x 512 bf16 = 32768 u32
    for (long i = gid; i < 32768; i += stride) ((int*)Hb)[i] = 0;
    if (gid < 256) flags[gid] = 0;
}

// ---------------- recurrence: 4 independent streams x 16 WGs ----------------
// Stream s owns batch rows [s*16, s*16+16); its recurrence is independent of
// other streams (LSTM mixes hidden dims, never batch rows). Member m of a
// stream owns h-cols [m*32, m*32+32); weights for K=768 register-resident.
// Per-step exchange: 16-row H slice via LLC —
//   produce: relaxed agent atomic u32 stores (sc1 -> coherence point; the
//            SAME primitive as every passing round's flag store)
//   -> __syncthreads (compiler emits s_waitcnt vmcnt(0) before s_barrier =>
//      all waves' stores ACKed)  -> tid0 relaxed atomic flag = t+1
//   consume: 16 lanes poll member flags relaxed (proven r3/r5/r8) ->
//            __syncthreads -> relaxed atomic u32 H loads (proven r8).
// No fences, no wbl2/inv, no cooperative launch (64 blocks co-resident).
__global__ __launch_bounds__(256, 1)
void lstm_rec(const u16* __restrict__ Xb, u16* __restrict__ Hb, int* __restrict__ flags,
              const u16* __restrict__ Wcat,
              const float* __restrict__ bi, const float* __restrict__ bf_,
              const float* __restrict__ bo, const float* __restrict__ bg,
              float* __restrict__ Hs, float* __restrict__ Cs) {
    const int s    = blockIdx.x >> 4;     // stream 0..3
    const int m    = blockIdx.x & 15;     // member 0..15
    const int tid  = threadIdx.x;
    const int lane = tid & 63;
    const int wave = tid >> 6;            // 4 waves split the 8 col-tiles
    const int c    = lane & 15;
    const int hi4  = lane >> 4;           // 0..3 (k-chunk)
    const int gate = c >> 2;              // 0=i 1=f 2=o 3=g
    const int hloc = c & 3;

    const int t0 = m * 8 + wave * 2;      // global col-tile indices (0..127)
    const int t1 = t0 + 1;
    const int h0 = t0 * 4 + hloc;         // hidden columns this lane combines
    const int h1 = t1 * 4 + hloc;

    const float* bp = (gate == 0) ? bi : (gate == 1) ? bf_ : (gate == 2) ? bo : bg;
    const float bias0 = bp[h0];
    const float bias1 = bp[h1];

    // ---- preload both col-tiles' B fragments (K=768) into registers ----
    bf16x8 B0[24], B1[24];
#pragma unroll
    for (int kt = 0; kt < 24; ++kt) {
        B0[kt] = *(const bf16x8*)(Wcat + (long)(t0 * 16 + c) * 768 + kt * 32 + hi4 * 8);
        B1[kt] = *(const bf16x8*)(Wcat + (long)(t1 * 16 + c) * 768 + kt * 32 + hi4 * 8);
    }

    const int srcbase = (lane & 48) | hloc;         // shfl gate-gather base

    // H exchange buffer (u32 view): [parity][stream][16 rows][256 u32]
    u32* Hb32 = (u32*)Hb;
    const int hbStream = s * (16 * HH / 2);         // u32 offset of stream
    const int hbPar = NSTREAM * 16 * HH / 2;        // parity stride in u32

    // ---- preload X fragments for t=0 (rows = stream rows, plain cached) ----
    bf16x8 xf[8];
    {
        const u16* xp = Xb + ((long)(s * 16 + c)) * II + hi4 * 8;
#pragma unroll
        for (int kt = 0; kt < 8; ++kt) xf[kt] = *(const bf16x8*)(xp + kt * 32);
    }

    float cst0[4] = {0.f, 0.f, 0.f, 0.f};
    float cst1[4] = {0.f, 0.f, 0.f, 0.f};

    for (int t = 0; t < TT; ++t) {
        // 1. issue ALL H loads first (relaxed agent atomics -> LLC, fresh)
        bf16x8 hf[16];
        {
            const u32* hp = Hb32 + (t & 1) * hbPar + hbStream + c * (HH / 2) + hi4 * 4;
#pragma unroll
            for (int kt = 0; kt < 16; ++kt) {
                union { u32 d[4]; bf16x8 v; } uu;
                uu.d[0] = __hip_atomic_load(hp + kt * 16 + 0, __ATOMIC_RELAXED, __HIP_MEMORY_SCOPE_AGENT);
                uu.d[1] = __hip_atomic_load(hp + kt * 16 + 1, __ATOMIC_RELAXED, __HIP_MEMORY_SCOPE_AGENT);
                uu.d[2] = __hip_atomic_load(hp + kt * 16 + 2, __ATOMIC_RELAXED, __HIP_MEMORY_SCOPE_AGENT);
                uu.d[3] = __hip_atomic_load(hp + kt * 16 + 3, __ATOMIC_RELAXED, __HIP_MEMORY_SCOPE_AGENT);
                hf[kt] = uu.v;
            }
        }

        // 2. X-part MFMAs (registers only — overlap H-load LLC latency)
        fx4 a00 = {bias0, bias0, bias0, bias0};
        fx4 a01 = {0.f, 0.f, 0.f, 0.f};
        fx4 a10 = {bias1, bias1, bias1, bias1};
        fx4 a11 = {0.f, 0.f, 0.f, 0.f};
#pragma unroll
        for (int kt = 0; kt < 8; ++kt) {
            if (kt & 1) {
                a01 = __builtin_amdgcn_mfma_f32_16x16x32_bf16(xf[kt], B0[kt], a01, 0, 0, 0);
                a11 = __builtin_amdgcn_mfma_f32_16x16x32_bf16(xf[kt], B1[kt], a11, 0, 0, 0);
            } else {
                a00 = __builtin_amdgcn_mfma_f32_16x16x32_bf16(xf[kt], B0[kt], a00, 0, 0, 0);
                a10 = __builtin_amdgcn_mfma_f32_16x16x32_bf16(xf[kt], B1[kt], a10, 0, 0, 0);
            }
        }

        // 3. prefetch next step's X tile into registers
        bf16x8 xf2[8];
        if (t < TT - 1) {
            const u16* xp = Xb + ((long)((t + 1) * BB + s * 16 + c)) * II + hi4 * 8;
#pragma unroll
            for (int kt = 0; kt < 8; ++kt) xf2[kt] = *(const bf16x8*)(xp + kt * 32);
        }

        // 4. H-part MFMAs
#pragma unroll
        for (int kt = 0; kt < 16; ++kt) {
            if (kt & 1) {
                a01 = __builtin_amdgcn_mfma_f32_16x16x32_bf16(hf[kt], B0[8 + kt], a01, 0, 0, 0);
                a11 = __builtin_amdgcn_mfma_f32_16x16x32_bf16(hf[kt], B1[8 + kt], a11, 0, 0, 0);
            } else {
                a00 = __builtin_amdgcn_mfma_f32_16x16x32_bf16(hf[kt], B0[8 + kt], a00, 0, 0, 0);
                a10 = __builtin_amdgcn_mfma_f32_16x16x32_bf16(hf[kt], B1[8 + kt], a10, 0, 0, 0);
            }
        }
        fx4 accA = a00 + a01;
        fx4 accB = a10 + a11;

        // 5. gather gate preacts + elementwise gate math (both tiles)
        float cnA[4], hnA[4], cnB[4], hnB[4];
#pragma unroll
        for (int r = 0; r < 4; ++r) {
            float pi = __shfl(accA[r], srcbase + 0);
            float pf = __shfl(accA[r], srcbase + 4);
            float po = __shfl(accA[r], srcbase + 8);
            float pg = __shfl(accA[r], srcbase + 12);
            float ig = fsig(pi), fg = fsig(pf), og = fsig(po), gg = ftanh(pg);
            float cv = fg * cst0[r] + ig * gg;
            cst0[r] = cv; cnA[r] = cv;
            hnA[r] = og * ftanh(cv);
        }
#pragma unroll
        for (int r = 0; r < 4; ++r) {
            float pi = __shfl(accB[r], srcbase + 0);
            float pf = __shfl(accB[r], srcbase + 4);
            float po = __shfl(accB[r], srcbase + 8);
            float pg = __shfl(accB[r], srcbase + 12);
            float ig = fsig(pi), fg = fsig(pf), og = fsig(po), gg = ftanh(pg);
            float cv = fg * cst1[r] + ig * gg;
            cst1[r] = cv; cnB[r] = cv;
            hnB[r] = og * ftanh(cv);
        }

        // 6. Hs/Cs fp32 stores (nontemporal). Full 64B lines per WG now:
        //    line h-span 16 is inside this WG's 32-col slice -> no RMW.
        if (c < 4) {
            float* HsT = Hs + (long)t * BB * HH + (long)(s * 16 + hi4 * 4) * HH;
            float* CsT = Cs + (long)t * BB * HH + (long)(s * 16 + hi4 * 4) * HH;
#pragma unroll
            for (int r = 0; r < 4; ++r) {
                __builtin_nontemporal_store(hnA[r], &HsT[(long)r * HH + h0]);
                __builtin_nontemporal_store(cnA[r], &CsT[(long)r * HH + h0]);
                __builtin_nontemporal_store(hnB[r], &HsT[(long)r * HH + h1]);
                __builtin_nontemporal_store(cnB[r], &CsT[(long)r * HH + h1]);
            }
        }

        if (t == TT - 1) break;   // last step: nobody consumes H_{t+1}

        // 7. pack bf16 pairs and publish H via relaxed agent atomic stores
        //    (sc1 -> LLC; ACK tracked by vmcnt)
        u32 pkA[4], pkB[4];
#pragma unroll
        for (int r = 0; r < 4; ++r) {
            float aHi = __shfl(hnA[r], lane | 1);
            float bHi = __shfl(hnB[r], lane | 1);
            pkA[r] = (u32)f2bf(hnA[r]) | ((u32)f2bf(aHi) << 16);
            pkB[r] = (u32)f2bf(hnB[r]) | ((u32)f2bf(bHi) << 16);
        }
        if ((c & 13) == 4) {      // lanes c==4 (hloc 0) and c==6 (hloc 2)
            u32* wp = Hb32 + ((t + 1) & 1) * hbPar + hbStream;
#pragma unroll
            for (int r = 0; r < 4; ++r) {
                int row = hi4 * 4 + r;
                __hip_atomic_store(wp + row * (HH / 2) + (h0 >> 1), pkA[r],
                                   __ATOMIC_RELAXED, __HIP_MEMORY_SCOPE_AGENT);
                __hip_atomic_store(wp + row * (HH / 2) + (h1 >> 1), pkB[r],
                                   __ATOMIC_RELAXED, __HIP_MEMORY_SCOPE_AGENT);
            }
        }

        // 8. WG join: barrier's s_waitcnt vmcnt(0) => all stores ACKed at LLC
        __syncthreads();
        if (tid == 0)
            __hip_atomic_store(&flags[blockIdx.x], t + 1,
                               __ATOMIC_RELAXED, __HIP_MEMORY_SCOPE_AGENT);

        // 9. wait for the 16 stream members (relaxed poll, proven primitive)
        if (tid < WGS_PER_STREAM) {
            while (__hip_atomic_load(&flags[s * 16 + tid], __ATOMIC_RELAXED,
                                     __HIP_MEMORY_SCOPE_AGENT) < t + 1)
                __builtin_amdgcn_s_sleep(1);
        }
        __syncthreads();
        __builtin_amdgcn_sched_barrier(0);   // pin next H loads below the poll

        // rotate X prefetch
#pragma unroll
        for (int kt = 0; kt < 8; ++kt) xf[kt] = xf2[kt];
    }
}

// ---------------- output GEMM: out = Hs @ WqT^T + bq ----------------
__global__ __launch_bounds__(256) void outgemm(const float* __restrict__ Hs,
                                               const u16* __restrict__ WqT,
                                               const float* __restrict__ bq,
                                               float* __restrict__ outp) {
    const int lane = threadIdx.x & 63, wave = threadIdx.x >> 6;
    const int cl = lane & 15, hi4 = lane >> 4;
    const int rowbase = blockIdx.x * 64 + wave * 16;
    const int colbase = blockIdx.y * 64;

    const float* Ap = Hs + (long)(rowbase + cl) * HH + hi4 * 8;
    fx4 acc[4];
#pragma unroll
    for (int n = 0; n < 4; ++n) acc[n] = (fx4){0.f, 0.f, 0.f, 0.f};

#pragma unroll
    for (int kt = 0; kt < 16; ++kt) {
        const float4* a4 = (const float4*)(Ap + kt * 32);
        float4 a0 = a4[0], a1 = a4[1];
        bf16x8 af;
        af[0] = (short)f2bf(a0.x); af[1] = (short)f2bf(a0.y);
        af[2] = (short)f2bf(a0.z); af[3] = (short)f2bf(a0.w);
        af[4] = (short)f2bf(a1.x); af[5] = (short)f2bf(a1.y);
        af[6] = (short)f2bf(a1.z); af[7] = (short)f2bf(a1.w);
#pragma unroll
        for (int n = 0; n < 4; ++n) {
            bf16x8 bfg = *(const bf16x8*)(WqT + (long)(colbase + n * 16 + cl) * HH + kt * 32 + hi4 * 8);
            acc[n] = __builtin_amdgcn_mfma_f32_16x16x32_bf16(af, bfg, acc[n], 0, 0, 0);
        }
    }
#pragma unroll
    for (int n = 0; n < 4; ++n) {
        int col = colbase + n * 16 + cl;
        float bv = bq[col];
#pragma unroll
        for (int r = 0; r < 4; ++r) {
            int row = rowbase + hi4 * 4 + r;
            outp[(long)row * OO + col] = acc[n][r] + bv;
        }
    }
}

extern "C" void kernel_launch(void* const* d_in, const int* in_sizes, int n_in,
                              void* d_out, int out_size, void* d_ws, size_t ws_size,
                              hipStream_t stream) {
    const float* X   = (const float*)d_in[0];
    const float* Wxi = (const float*)d_in[1];
    const float* Wxf = (const float*)d_in[2];
    const float* Wxo = (const float*)d_in[3];
    const float* Wxg = (const float*)d_in[4];
    const float* Whi = (const float*)d_in[5];
    const float* Whf = (const float*)d_in[6];
    const float* Who = (const float*)d_in[7];
    const float* Whg = (const float*)d_in[8];
    const float* bi  = (const float*)d_in[9];
    const float* bf_ = (const float*)d_in[10];
    const float* bo  = (const float*)d_in[11];
    const float* bg  = (const float*)d_in[12];
    const float* Whq = (const float*)d_in[13];
    const float* bq  = (const float*)d_in[14];

    float* outp = (float*)d_out;
    float* Hs = outp + (size_t)TT * BB * OO;          // 8388608
    float* Cs = Hs   + (size_t)TT * BB * HH;          // +16777216

    u16* Xb   = (u16*)d_ws;                           // 8388608 u16
    u16* WqT  = Xb + (size_t)TT * BB * II;            // 131072 u16
    u16* Wcat = WqT + (size_t)OO * HH;                // 1572864 u16
    u16* Hb   = Wcat + (size_t)2048 * 768;            // 65536 u16 (2 par x 4 strm)
    int* flags = (int*)(Hb + (size_t)65536);          // 256 ints

    prep_kernel<<<2048, 256, 0, stream>>>(X, Whq, Wxi, Wxf, Wxo, Wxg,
                                          Whi, Whf, Who, Whg,
                                          Xb, WqT, Wcat, Hb, flags);

    lstm_rec<<<dim3(GRID_WG), dim3(256), 0, stream>>>(
        Xb, Hb, flags, Wcat, bi, bf_, bo, bg, Hs, Cs);

    outgemm<<<dim3(512, 4), 256, 0, stream>>>(Hs, WqT, bq, outp);
}